// Round 1
// baseline (2259.677 us; speedup 1.0000x reference)
//
#include <hip/hip_runtime.h>

#define BROWS 65536
#define DDIM 256
#define MCODES 1024
#define TS 132  // LDS row stride (floats): 132*4=528B, 16B aligned; 8-way write / 4-way b-read conflicts tolerated

// ---------------- Kernel 1: numpy-exact pairwise row norms + zero-init ----------------
// numpy pairwise sum, n=256: P(a,256) = P(a,128) + P(a+128,128);
// P(*,128): r_j = a[j] + a[8+j] + ... + a[120+j] (j=0..7, sequential), then
// ((r0+r1)+(r2+r3)) + ((r4+r5)+(r6+r7)).
// 16 lanes per row: lanes 0..7 -> first 128, lanes 8..15 -> second 128.
__global__ __launch_bounds__(256)
void norms_init_kernel(const float* __restrict__ x, const float* __restrict__ emb,
                       float* __restrict__ xnorm, float* __restrict__ enorm,
                       float* __restrict__ counts, float* __restrict__ loss_acc) {
  int t = blockIdx.x * 256 + threadIdx.x;
  if (t < MCODES) counts[t] = 0.0f;
  if (t < 2) loss_acc[t] = 0.0f;
  int row = t >> 4;
  int lane = t & 15;
  const float* p;
  float* dst;
  int r;
  if (row < BROWS) { p = x + (size_t)row * DDIM; dst = xnorm; r = row; }
  else             { p = emb + (size_t)(row - BROWS) * DDIM; dst = enorm; r = row - BROWS; }
  int half = (lane >> 3) & 1;
  int j = lane & 7;
  const float* q = p + half * 128 + j;
  float v = q[0];
  float acc = __fmul_rn(v, v);          // square rounded separately (no fma fuse) like np x**2
  #pragma unroll
  for (int i = 1; i < 16; ++i) {
    v = q[i * 8];
    acc = __fadd_rn(acc, __fmul_rn(v, v));
  }
  float o;
  o = __shfl_xor(acc, 1, 64); acc = __fadd_rn(acc, o);  // (r0+r1) etc.
  o = __shfl_xor(acc, 2, 64); acc = __fadd_rn(acc, o);  // (r0+r1)+(r2+r3)
  o = __shfl_xor(acc, 4, 64); acc = __fadd_rn(acc, o);  // full 128-block
  o = __shfl_xor(acc, 8, 64); acc = __fadd_rn(acc, o);  // P_low + P_high
  if (lane == 0) dst[r] = acc;
}

// ---------------- Kernel 2: tiled fp32 score + argmin ----------------
// WG tile: 128 rows x (1024 m in 8 chunks of 128), K chunks of 64.
// micro-tile 8x8 per thread (tx=m-group, ty=row-group). Scores never stored:
// s = fl(fl(enorm_m + xnorm_b) - 2*dot), strict < argmin, lowest-index ties.
__global__ __launch_bounds__(256, 2)
void score_argmin_kernel(const float* __restrict__ x, const float* __restrict__ emb,
                         const float* __restrict__ xnorm, const float* __restrict__ enorm,
                         int* __restrict__ idx_out, float* __restrict__ out_idx_f) {
  __shared__ float xs[64][TS];      // k-major: xs[k][r]
  __shared__ float es[64][TS];      // k-major: es[k][m]
  __shared__ float enorm_s[MCODES];

  int tid = threadIdx.x;
  int rowBase = blockIdx.x * 128;
  int tx = tid & 15, ty = tid >> 4;

  for (int i = tid; i < MCODES; i += 256) enorm_s[i] = enorm[i];

  float xn[8];
  #pragma unroll
  for (int i = 0; i < 8; ++i) xn[i] = xnorm[rowBase + ty * 8 + i];

  float best[8];
  int bidx[8];
  #pragma unroll
  for (int i = 0; i < 8; ++i) { best[i] = 3.4e38f; bidx[i] = 0; }

  int sk = tid & 63;    // staging k within chunk
  int sr0 = tid >> 6;   // staging row 0..3 (+4*i)

  for (int mc = 0; mc < 8; ++mc) {
    float acc[8][8];
    #pragma unroll
    for (int i = 0; i < 8; ++i)
      #pragma unroll
      for (int jj = 0; jj < 8; ++jj) acc[i][jj] = 0.0f;

    for (int kc = 0; kc < 4; ++kc) {
      __syncthreads();
      const float* xp = x + (size_t)(rowBase + sr0) * DDIM + kc * 64 + sk;
      const float* ep = emb + (size_t)(mc * 128 + sr0) * DDIM + kc * 64 + sk;
      #pragma unroll 8
      for (int i = 0; i < 32; ++i) {
        xs[sk][sr0 + i * 4] = xp[(size_t)(i * 4) * DDIM];
        es[sk][sr0 + i * 4] = ep[(size_t)(i * 4) * DDIM];
      }
      __syncthreads();
      #pragma unroll 2
      for (int k = 0; k < 64; ++k) {
        float4 a0 = *(const float4*)&xs[k][ty * 8];
        float4 a1 = *(const float4*)&xs[k][ty * 8 + 4];
        float4 b0 = *(const float4*)&es[k][tx * 8];
        float4 b1 = *(const float4*)&es[k][tx * 8 + 4];
        float av[8] = {a0.x, a0.y, a0.z, a0.w, a1.x, a1.y, a1.z, a1.w};
        float bv[8] = {b0.x, b0.y, b0.z, b0.w, b1.x, b1.y, b1.z, b1.w};
        #pragma unroll
        for (int i = 0; i < 8; ++i)
          #pragma unroll
          for (int jj = 0; jj < 8; ++jj)
            acc[i][jj] = fmaf(av[i], bv[jj], acc[i][jj]);
      }
    }
    // epilogue: scores + argmin update (m ascending => strict < keeps first)
    #pragma unroll
    for (int jj = 0; jj < 8; ++jj) {
      int m = mc * 128 + tx * 8 + jj;
      float en = enorm_s[m];
      #pragma unroll
      for (int i = 0; i < 8; ++i) {
        float tsum = __fadd_rn(en, xn[i]);           // fl(enorm + xnorm) -- the grid-rounding step
        float s = __fadd_rn(tsum, -2.0f * acc[i][jj]); // 2*acc exact; single rounded subtract
        if (s < best[i]) { best[i] = s; bidx[i] = m; }
      }
    }
  }

  // cross-thread reduction over the 16 tx candidates per row
  __syncthreads();
  float* redv = (float*)&xs[0][0];
  int* redi = (int*)&es[0][0];
  #pragma unroll
  for (int i = 0; i < 8; ++i) {
    redv[(ty * 8 + i) * 16 + tx] = best[i];
    redi[(ty * 8 + i) * 16 + tx] = bidx[i];
  }
  __syncthreads();
  if (tid < 128) {
    float bv = redv[tid * 16];
    int bi = redi[tid * 16];
    for (int c = 1; c < 16; ++c) {
      float v = redv[tid * 16 + c];
      int vi = redi[tid * 16 + c];
      if (v < bv || (v == bv && vi < bi)) { bv = v; bi = vi; }
    }
    idx_out[rowBase + tid] = bi;
    out_idx_f[rowBase + tid] = (float)bi;
  }
}

// ---------------- Kernel 3: gather + quantized_st + loss partials + counts ----------------
__global__ __launch_bounds__(256)
void gather_loss_kernel(const float* __restrict__ x, const float* __restrict__ emb,
                        const int* __restrict__ idx, float* __restrict__ qout,
                        float* __restrict__ counts, float* __restrict__ loss_acc) {
  int row = blockIdx.x * 4 + (threadIdx.x >> 6);
  int lane = threadIdx.x & 63;
  int id = idx[row];
  const float4* xr = (const float4*)(x + (size_t)row * DDIM);
  const float4* er = (const float4*)(emb + (size_t)id * DDIM);
  float4 xv = xr[lane];
  float4 ev = er[lane];
  float4 q;
  q.x = __fadd_rn(xv.x, __fadd_rn(ev.x, -xv.x));  // x + (q - x), two rounded adds like ref
  q.y = __fadd_rn(xv.y, __fadd_rn(ev.y, -xv.y));
  q.z = __fadd_rn(xv.z, __fadd_rn(ev.z, -xv.z));
  q.w = __fadd_rn(xv.w, __fadd_rn(ev.w, -xv.w));
  ((float4*)qout)[(size_t)row * 64 + lane] = q;

  float d0 = xv.x - ev.x, d1 = xv.y - ev.y, d2 = xv.z - ev.z, d3 = xv.w - ev.w;
  float loc = d0 * d0 + d1 * d1 + d2 * d2 + d3 * d3;
  float la = fabsf(xv.x) + fabsf(xv.y) + fabsf(xv.z) + fabsf(xv.w);
  #pragma unroll
  for (int off = 32; off > 0; off >>= 1) {
    loc += __shfl_xor(loc, off, 64);
    la += __shfl_xor(la, off, 64);
  }
  if (lane == 0) {
    float np = (la > 0.0f) ? 1.0f : 0.0f;
    atomicAdd(&loss_acc[0], (loc * (1.0f / 256.0f)) * np);
    atomicAdd(&loss_acc[1], np);
    atomicAdd(&counts[id], 1.0f);
  }
}

// ---------------- Kernel 4: finalize loss + perplexity ----------------
__global__ __launch_bounds__(256)
void finalize_kernel(const float* __restrict__ counts, const float* __restrict__ loss_acc,
                     float* __restrict__ out_loss, float* __restrict__ out_perp) {
  __shared__ float red[256];
  int t = threadIdx.x;
  float sum = 0.0f;
  for (int m = t; m < MCODES; m += 256) {
    float p = counts[m] * (1.0f / 65536.0f);
    sum += p * logf(p + 1e-10f);
  }
  red[t] = sum;
  __syncthreads();
  for (int s = 128; s > 0; s >>= 1) {
    if (t < s) red[t] += red[t + s];
    __syncthreads();
  }
  if (t == 0) {
    *out_perp = expf(-red[0]);
    *out_loss = 0.25f * loss_acc[0] / loss_acc[1];
  }
}

extern "C" void kernel_launch(void* const* d_in, const int* in_sizes, int n_in,
                              void* d_out, int out_size, void* d_ws, size_t ws_size,
                              hipStream_t stream) {
  (void)in_sizes; (void)n_in; (void)out_size; (void)ws_size;
  const float* x = (const float*)d_in[0];
  const float* emb = (const float*)d_in[1];

  float* out = (float*)d_out;
  float* qst = out;                              // 16777216 floats
  float* out_loss = out + 16777216;              // 1
  float* out_idxf = out + 16777217;              // 65536
  float* out_perp = out + 16842753;              // 1

  float* ws = (float*)d_ws;
  float* xnorm = ws;                 // 65536
  float* enorm = ws + 65536;         // 1024
  int* idx = (int*)(ws + 66560);     // 65536
  float* counts = ws + 132096;       // 1024
  float* loss_acc = ws + 133120;     // 2

  norms_init_kernel<<<4160, 256, 0, stream>>>(x, emb, xnorm, enorm, counts, loss_acc);
  score_argmin_kernel<<<512, 256, 0, stream>>>(x, emb, xnorm, enorm, idx, out_idxf);
  gather_loss_kernel<<<16384, 256, 0, stream>>>(x, emb, idx, qst, counts, loss_acc);
  finalize_kernel<<<1, 256, 0, stream>>>(counts, loss_acc, out_loss, out_perp);
}

// Round 2
// 569.690 us; speedup vs baseline: 3.9665x; 3.9665x over previous
//
#include <hip/hip_runtime.h>

#define BROWS 65536
#define DDIM 256
#define MCODES 1024
#define TS 132  // LDS row stride (floats)

// ---------------- Kernel 1: numpy-exact pairwise row norms + zero-init ----------------
__global__ __launch_bounds__(256)
void norms_init_kernel(const float* __restrict__ x, const float* __restrict__ emb,
                       float* __restrict__ xnorm, float* __restrict__ enorm,
                       float* __restrict__ counts) {
  int t = blockIdx.x * 256 + threadIdx.x;
  if (t < MCODES) counts[t] = 0.0f;
  int row = t >> 4;
  int lane = t & 15;
  const float* p;
  float* dst;
  int r;
  if (row < BROWS) { p = x + (size_t)row * DDIM; dst = xnorm; r = row; }
  else             { p = emb + (size_t)(row - BROWS) * DDIM; dst = enorm; r = row - BROWS; }
  int half = (lane >> 3) & 1;
  int j = lane & 7;
  const float* q = p + half * 128 + j;
  float v = q[0];
  float acc = __fmul_rn(v, v);
  #pragma unroll
  for (int i = 1; i < 16; ++i) {
    v = q[i * 8];
    acc = __fadd_rn(acc, __fmul_rn(v, v));
  }
  float o;
  o = __shfl_xor(acc, 1, 64); acc = __fadd_rn(acc, o);
  o = __shfl_xor(acc, 2, 64); acc = __fadd_rn(acc, o);
  o = __shfl_xor(acc, 4, 64); acc = __fadd_rn(acc, o);
  o = __shfl_xor(acc, 8, 64); acc = __fadd_rn(acc, o);
  if (lane == 0) dst[r] = acc;
}

// ---------------- Kernel 2: tiled fp32 score + argmin (unchanged, validated) ----------------
__global__ __launch_bounds__(256, 2)
void score_argmin_kernel(const float* __restrict__ x, const float* __restrict__ emb,
                         const float* __restrict__ xnorm, const float* __restrict__ enorm,
                         int* __restrict__ idx_out, float* __restrict__ out_idx_f) {
  __shared__ float xs[64][TS];
  __shared__ float es[64][TS];
  __shared__ float enorm_s[MCODES];

  int tid = threadIdx.x;
  int rowBase = blockIdx.x * 128;
  int tx = tid & 15, ty = tid >> 4;

  for (int i = tid; i < MCODES; i += 256) enorm_s[i] = enorm[i];

  float xn[8];
  #pragma unroll
  for (int i = 0; i < 8; ++i) xn[i] = xnorm[rowBase + ty * 8 + i];

  float best[8];
  int bidx[8];
  #pragma unroll
  for (int i = 0; i < 8; ++i) { best[i] = 3.4e38f; bidx[i] = 0; }

  int sk = tid & 63;
  int sr0 = tid >> 6;

  for (int mc = 0; mc < 8; ++mc) {
    float acc[8][8];
    #pragma unroll
    for (int i = 0; i < 8; ++i)
      #pragma unroll
      for (int jj = 0; jj < 8; ++jj) acc[i][jj] = 0.0f;

    for (int kc = 0; kc < 4; ++kc) {
      __syncthreads();
      const float* xp = x + (size_t)(rowBase + sr0) * DDIM + kc * 64 + sk;
      const float* ep = emb + (size_t)(mc * 128 + sr0) * DDIM + kc * 64 + sk;
      #pragma unroll 8
      for (int i = 0; i < 32; ++i) {
        xs[sk][sr0 + i * 4] = xp[(size_t)(i * 4) * DDIM];
        es[sk][sr0 + i * 4] = ep[(size_t)(i * 4) * DDIM];
      }
      __syncthreads();
      #pragma unroll 2
      for (int k = 0; k < 64; ++k) {
        float4 a0 = *(const float4*)&xs[k][ty * 8];
        float4 a1 = *(const float4*)&xs[k][ty * 8 + 4];
        float4 b0 = *(const float4*)&es[k][tx * 8];
        float4 b1 = *(const float4*)&es[k][tx * 8 + 4];
        float av[8] = {a0.x, a0.y, a0.z, a0.w, a1.x, a1.y, a1.z, a1.w};
        float bv[8] = {b0.x, b0.y, b0.z, b0.w, b1.x, b1.y, b1.z, b1.w};
        #pragma unroll
        for (int i = 0; i < 8; ++i)
          #pragma unroll
          for (int jj = 0; jj < 8; ++jj)
            acc[i][jj] = fmaf(av[i], bv[jj], acc[i][jj]);
      }
    }
    #pragma unroll
    for (int jj = 0; jj < 8; ++jj) {
      int m = mc * 128 + tx * 8 + jj;
      float en = enorm_s[m];
      #pragma unroll
      for (int i = 0; i < 8; ++i) {
        float tsum = __fadd_rn(en, xn[i]);
        float s = __fadd_rn(tsum, -2.0f * acc[i][jj]);
        if (s < best[i]) { best[i] = s; bidx[i] = m; }
      }
    }
  }

  __syncthreads();
  float* redv = (float*)&xs[0][0];
  int* redi = (int*)&es[0][0];
  #pragma unroll
  for (int i = 0; i < 8; ++i) {
    redv[(ty * 8 + i) * 16 + tx] = best[i];
    redi[(ty * 8 + i) * 16 + tx] = bidx[i];
  }
  __syncthreads();
  if (tid < 128) {
    float bv = redv[tid * 16];
    int bi = redi[tid * 16];
    for (int c = 1; c < 16; ++c) {
      float v = redv[tid * 16 + c];
      int vi = redi[tid * 16 + c];
      if (v < bv || (v == bv && vi < bi)) { bv = v; bi = vi; }
    }
    idx_out[rowBase + tid] = bi;
    out_idx_f[rowBase + tid] = (float)bi;
  }
}

// ---------------- Kernel 3: gather + quantized_st + PER-BLOCK loss partials + counts ----------------
// 256 threads = 4 waves = 4 rows per iteration; 4 iterations -> 16 rows/block.
// No same-address global atomics: block partials to ws, reduced in finalize.
__global__ __launch_bounds__(256)
void gather_loss_kernel(const float* __restrict__ x, const float* __restrict__ emb,
                        const int* __restrict__ idx, float* __restrict__ qout,
                        float* __restrict__ counts,
                        float* __restrict__ loss_part, float* __restrict__ np_part) {
  int lane = threadIdx.x & 63;
  int wav = threadIdx.x >> 6;
  float lsum = 0.0f, nsum = 0.0f;
  #pragma unroll
  for (int it = 0; it < 4; ++it) {
    int row = blockIdx.x * 16 + it * 4 + wav;
    int id = idx[row];
    const float4* xr = (const float4*)(x + (size_t)row * DDIM);
    const float4* er = (const float4*)(emb + (size_t)id * DDIM);
    float4 xv = xr[lane];
    float4 ev = er[lane];
    float4 q;
    q.x = __fadd_rn(xv.x, __fadd_rn(ev.x, -xv.x));
    q.y = __fadd_rn(xv.y, __fadd_rn(ev.y, -xv.y));
    q.z = __fadd_rn(xv.z, __fadd_rn(ev.z, -xv.z));
    q.w = __fadd_rn(xv.w, __fadd_rn(ev.w, -xv.w));
    ((float4*)qout)[(size_t)row * 64 + lane] = q;

    float d0 = xv.x - ev.x, d1 = xv.y - ev.y, d2 = xv.z - ev.z, d3 = xv.w - ev.w;
    float loc = d0 * d0 + d1 * d1 + d2 * d2 + d3 * d3;
    float la = fabsf(xv.x) + fabsf(xv.y) + fabsf(xv.z) + fabsf(xv.w);
    #pragma unroll
    for (int off = 32; off > 0; off >>= 1) {
      loc += __shfl_xor(loc, off, 64);
      la += __shfl_xor(la, off, 64);
    }
    if (lane == 0) {
      float np = (la > 0.0f) ? 1.0f : 0.0f;
      lsum += (loc * (1.0f / 256.0f)) * np;
      nsum += np;
      atomicAdd(&counts[id], 1.0f);  // 1024 distinct lines -> parallel
    }
  }
  __shared__ float red[8];
  if (lane == 0) { red[wav] = lsum; red[4 + wav] = nsum; }
  __syncthreads();
  if (threadIdx.x == 0) {
    loss_part[blockIdx.x] = (red[0] + red[1]) + (red[2] + red[3]);
    np_part[blockIdx.x] = (red[4] + red[5]) + (red[6] + red[7]);
  }
}

// ---------------- Kernel 4: finalize loss + perplexity ----------------
#define NPART 4096
__global__ __launch_bounds__(256)
void finalize_kernel(const float* __restrict__ counts,
                     const float* __restrict__ loss_part, const float* __restrict__ np_part,
                     float* __restrict__ out_loss, float* __restrict__ out_perp) {
  __shared__ float red[768];
  int t = threadIdx.x;
  float esum = 0.0f, lsum = 0.0f, nsum = 0.0f;
  for (int m = t; m < MCODES; m += 256) {
    float p = counts[m] * (1.0f / 65536.0f);
    esum += p * logf(p + 1e-10f);
  }
  for (int i = t; i < NPART; i += 256) {
    lsum += loss_part[i];
    nsum += np_part[i];
  }
  red[t] = esum; red[256 + t] = lsum; red[512 + t] = nsum;
  __syncthreads();
  for (int s = 128; s > 0; s >>= 1) {
    if (t < s) {
      red[t] += red[t + s];
      red[256 + t] += red[256 + t + s];
      red[512 + t] += red[512 + t + s];
    }
    __syncthreads();
  }
  if (t == 0) {
    *out_perp = expf(-red[0]);
    *out_loss = 0.25f * red[256] / red[512];
  }
}

extern "C" void kernel_launch(void* const* d_in, const int* in_sizes, int n_in,
                              void* d_out, int out_size, void* d_ws, size_t ws_size,
                              hipStream_t stream) {
  (void)in_sizes; (void)n_in; (void)out_size; (void)ws_size;
  const float* x = (const float*)d_in[0];
  const float* emb = (const float*)d_in[1];

  float* out = (float*)d_out;
  float* qst = out;                              // 16777216 floats
  float* out_loss = out + 16777216;              // 1
  float* out_idxf = out + 16777217;              // 65536
  float* out_perp = out + 16842753;              // 1

  float* ws = (float*)d_ws;
  float* xnorm = ws;                   // 65536
  float* enorm = ws + 65536;           // 1024
  int* idx = (int*)(ws + 66560);       // 65536
  float* counts = ws + 132096;         // 1024
  float* loss_part = ws + 133120;      // 4096
  float* np_part = ws + 137216;        // 4096

  norms_init_kernel<<<4160, 256, 0, stream>>>(x, emb, xnorm, enorm, counts);
  score_argmin_kernel<<<512, 256, 0, stream>>>(x, emb, xnorm, enorm, idx, out_idxf);
  gather_loss_kernel<<<4096, 256, 0, stream>>>(x, emb, idx, qst, counts, loss_part, np_part);
  finalize_kernel<<<1, 256, 0, stream>>>(counts, loss_part, np_part, out_loss, out_perp);
}

// Round 3
// 373.477 us; speedup vs baseline: 6.0504x; 1.5254x over previous
//
#include <hip/hip_runtime.h>

#define BROWS 65536
#define DDIM 256
#define MCODES 1024
#define EPS_MARGIN 1e-4f

typedef __attribute__((ext_vector_type(8))) short short8;   // bf16x8 MFMA frag
typedef __attribute__((ext_vector_type(4))) float float4v;  // fp32x4 acc

__device__ inline unsigned short f2bf_rne(float f) {
  unsigned u = __float_as_uint(f);
  unsigned r = u + 0x7FFFu + ((u >> 16) & 1u);
  return (unsigned short)(r >> 16);
}

// ---------------- Kernel 1: numpy-exact pairwise row norms + zero-init (validated) ----------------
__global__ __launch_bounds__(256)
void norms_init_kernel(const float* __restrict__ x, const float* __restrict__ emb,
                       float* __restrict__ xnorm, float* __restrict__ enorm,
                       float* __restrict__ counts, int* __restrict__ nflag) {
  int t = blockIdx.x * 256 + threadIdx.x;
  if (t < MCODES) counts[t] = 0.0f;
  if (t == 0) *nflag = 0;
  int row = t >> 4;
  int lane = t & 15;
  const float* p;
  float* dst;
  int r;
  if (row < BROWS) { p = x + (size_t)row * DDIM; dst = xnorm; r = row; }
  else             { p = emb + (size_t)(row - BROWS) * DDIM; dst = enorm; r = row - BROWS; }
  int half = (lane >> 3) & 1;
  int j = lane & 7;
  const float* q = p + half * 128 + j;
  float v = q[0];
  float acc = __fmul_rn(v, v);
  #pragma unroll
  for (int i = 1; i < 16; ++i) {
    v = q[i * 8];
    acc = __fadd_rn(acc, __fmul_rn(v, v));
  }
  float o;
  o = __shfl_xor(acc, 1, 64); acc = __fadd_rn(acc, o);
  o = __shfl_xor(acc, 2, 64); acc = __fadd_rn(acc, o);
  o = __shfl_xor(acc, 4, 64); acc = __fadd_rn(acc, o);
  o = __shfl_xor(acc, 8, 64); acc = __fadd_rn(acc, o);
  if (lane == 0) dst[r] = acc;
}

// ---------------- Kernel 2: e-fragment image precompute ----------------
// Image: [cc 32][kstep 8][spl 2][tile 2][lane 64] x 16B. chunk t: lane=t&63,
// tile=(t>>6)&1, spl=(t>>7)&1, kstep=(t>>8)&7, cc=t>>11.
// code = cc*32 + tile*16 + (lane&15); k = kstep*32 + (lane>>4)*8 + j.
__global__ __launch_bounds__(256)
void eimg_kernel(const float* __restrict__ emb, unsigned short* __restrict__ img) {
  int t = blockIdx.x * 256 + threadIdx.x;  // 65536 chunks
  int lane = t & 63;
  int tile = (t >> 6) & 1;
  int spl = (t >> 7) & 1;
  int kstep = (t >> 8) & 7;
  int cc = t >> 11;
  int code = cc * 32 + tile * 16 + (lane & 15);
  int kb = kstep * 32 + (lane >> 4) * 8;
  const float* src = emb + (size_t)code * DDIM + kb;
  union { unsigned short u[8]; uint4 v; } out;
  #pragma unroll
  for (int j = 0; j < 8; ++j) {
    float f = src[j];
    unsigned short h = f2bf_rne(f);
    if (spl == 0) out.u[j] = h;
    else {
      float r = __fadd_rn(f, -__uint_as_float((unsigned)h << 16));
      out.u[j] = f2bf_rne(r);
    }
  }
  ((uint4*)img)[t] = out.v;
}

// ---------------- Kernel 3: MFMA split-bf16 score + argmin + flag ----------------
// WG 256 = 4 waves x 32 rows = 128 rows. Wave tile: 32 rows x 32 codes/cc-iter,
// cc loops 32 chunks. A-frags (x splits) in registers for all K. B-frags staged
// global_load_lds double-buffered, lane-linear (conflict-free).
__global__ __launch_bounds__(256, 2)
void score_kernel(const float* __restrict__ x, const float* __restrict__ xnorm,
                  const float* __restrict__ enorm_g, const unsigned short* __restrict__ eimg,
                  int* __restrict__ idx_out, float* __restrict__ out_idxf,
                  int* __restrict__ nflag, int* __restrict__ flist) {
  __shared__ __align__(16) unsigned short ebuf[2][2048];  // 2 x 4KB
  __shared__ float enorm_s[MCODES];

  int tid = threadIdx.x;
  int w = tid >> 6;
  int lane = tid & 63;
  int quad = lane >> 4;
  int rowBase = blockIdx.x * 128;
  int waveRow = rowBase + w * 32;

  for (int i = tid; i < MCODES; i += 256) enorm_s[i] = enorm_g[i];

  // ---- A-frag preload: rows waveRow + rg*16 + (lane&15), k = ks*32 + quad*8 + j ----
  short8 xh[2][8], xl[2][8];
  const float* xbase = x + (size_t)(waveRow + (lane & 15)) * DDIM + quad * 8;
  #pragma unroll
  for (int rg = 0; rg < 2; ++rg) {
    #pragma unroll
    for (int ks = 0; ks < 8; ++ks) {
      const float4* p = (const float4*)(xbase + rg * 16 * DDIM + ks * 32);
      float4 v0 = p[0], v1 = p[1];
      float vv[8] = {v0.x, v0.y, v0.z, v0.w, v1.x, v1.y, v1.z, v1.w};
      short8 h8, l8;
      #pragma unroll
      for (int j = 0; j < 8; ++j) {
        unsigned short h = f2bf_rne(vv[j]);
        h8[j] = (short)h;
        float r = __fadd_rn(vv[j], -__uint_as_float((unsigned)h << 16));
        l8[j] = (short)f2bf_rne(r);
      }
      xh[rg][ks] = h8;
      xl[rg][ks] = l8;
    }
  }

  float xn[2][4];
  #pragma unroll
  for (int rg = 0; rg < 2; ++rg)
    #pragma unroll
    for (int reg = 0; reg < 4; ++reg)
      xn[rg][reg] = xnorm[waveRow + rg * 16 + quad * 4 + reg];

  float b1[2][4], b2[2][4];
  int i1[2][4];
  #pragma unroll
  for (int rg = 0; rg < 2; ++rg)
    #pragma unroll
    for (int reg = 0; reg < 4; ++reg) { b1[rg][reg] = 3.4e38f; b2[rg][reg] = 3.4e38f; i1[rg][reg] = 0; }

  // stage(step, buf): wave w loads its 1KB chunk, lane-linear
  #define STAGE(stp, bf) do { \
    const unsigned short* g_ = eimg + (size_t)(stp) * 2048 + w * 512 + lane * 8; \
    unsigned short* l_ = &ebuf[(bf)][w * 512]; \
    __builtin_amdgcn_global_load_lds((const __attribute__((address_space(1))) unsigned int*)g_, \
                                     (__attribute__((address_space(3))) unsigned int*)l_, 16, 0, 0); \
  } while (0)

  STAGE(0, 0);

  for (int cc = 0; cc < 32; ++cc) {
    float4v acc[2][2];
    #pragma unroll
    for (int rg = 0; rg < 2; ++rg)
      #pragma unroll
      for (int t2 = 0; t2 < 2; ++t2) acc[rg][t2] = (float4v){0.f, 0.f, 0.f, 0.f};

    #pragma unroll
    for (int ks = 0; ks < 8; ++ks) {
      int step = cc * 8 + ks;
      int buf = ks & 1;
      __syncthreads();                     // stage(step) complete; prev compute done
      if (step < 255) STAGE(step + 1, buf ^ 1);
      short8 eh[2], el[2];
      #pragma unroll
      for (int t2 = 0; t2 < 2; ++t2) {
        eh[t2] = *(const short8*)&ebuf[buf][0 * 1024 + t2 * 512 + lane * 8];
        el[t2] = *(const short8*)&ebuf[buf][1 * 1024 + t2 * 512 + lane * 8];
      }
      #pragma unroll
      for (int rg = 0; rg < 2; ++rg)
        #pragma unroll
        for (int t2 = 0; t2 < 2; ++t2) {
          acc[rg][t2] = __builtin_amdgcn_mfma_f32_16x16x32_bf16(xh[rg][ks], eh[t2], acc[rg][t2], 0, 0, 0);
          acc[rg][t2] = __builtin_amdgcn_mfma_f32_16x16x32_bf16(xl[rg][ks], eh[t2], acc[rg][t2], 0, 0, 0);
          acc[rg][t2] = __builtin_amdgcn_mfma_f32_16x16x32_bf16(xh[rg][ks], el[t2], acc[rg][t2], 0, 0, 0);
        }
    }

    // epilogue: scores + best/second-best (codes ascending: t2 then cc)
    #pragma unroll
    for (int t2 = 0; t2 < 2; ++t2) {
      int m = cc * 32 + t2 * 16 + (lane & 15);
      float en = enorm_s[m];
      #pragma unroll
      for (int rg = 0; rg < 2; ++rg)
        #pragma unroll
        for (int reg = 0; reg < 4; ++reg) {
          float T = __fadd_rn(en, xn[rg][reg]);
          float s = __fadd_rn(T, __fmul_rn(-2.0f, acc[rg][t2][reg]));
          if (s < b1[rg][reg]) { b2[rg][reg] = b1[rg][reg]; b1[rg][reg] = s; i1[rg][reg] = m; }
          else { b2[rg][reg] = fminf(b2[rg][reg], s); }
        }
    }
  }

  // cross-lane argmin over the 16 cols (lanes within a quad group)
  #pragma unroll
  for (int off = 1; off < 16; off <<= 1) {
    #pragma unroll
    for (int rg = 0; rg < 2; ++rg)
      #pragma unroll
      for (int reg = 0; reg < 4; ++reg) {
        float ob1 = __shfl_xor(b1[rg][reg], off, 64);
        float ob2 = __shfl_xor(b2[rg][reg], off, 64);
        int oi = __shfl_xor(i1[rg][reg], off, 64);
        float cb1 = b1[rg][reg], cb2 = b2[rg][reg];
        int ci = i1[rg][reg];
        float nb1, nb2; int ni;
        if (ob1 < cb1)      { nb1 = ob1; ni = oi; nb2 = fminf(cb1, ob2); }
        else if (cb1 < ob1) { nb1 = cb1; ni = ci; nb2 = fminf(ob1, cb2); }
        else                { nb1 = cb1; ni = min(ci, oi); nb2 = cb1; }  // tie -> flag
        b1[rg][reg] = nb1; b2[rg][reg] = nb2; i1[rg][reg] = ni;
      }
  }

  if ((lane & 15) == 0) {
    #pragma unroll
    for (int rg = 0; rg < 2; ++rg)
      #pragma unroll
      for (int reg = 0; reg < 4; ++reg) {
        int row = waveRow + rg * 16 + quad * 4 + reg;
        int bi = i1[rg][reg];
        idx_out[row] = bi;
        out_idxf[row] = (float)bi;
        if (__fadd_rn(b2[rg][reg], -b1[rg][reg]) <= EPS_MARGIN) {
          int p = atomicAdd(nflag, 1);
          flist[p] = row;
        }
      }
  }
  #undef STAGE
}

// ---------------- Kernel 4: exact fp32 rescore for flagged rows (rare) ----------------
// Bit-identical formula to the validated round-1/2 kernel: sequential fmaf k=0..255,
// s = fl(fl(en+xn) - 2*d), strict-<-with-lowest-index argmin.
__global__ __launch_bounds__(256)
void rescore_kernel(const float* __restrict__ x, const float* __restrict__ emb,
                    const float* __restrict__ xnorm, const float* __restrict__ enorm,
                    int* __restrict__ idx_out, float* __restrict__ out_idxf,
                    const int* __restrict__ nflag, const int* __restrict__ flist) {
  __shared__ float xrow[DDIM];
  __shared__ float rv[256];
  __shared__ int ri[256];
  int tid = threadIdx.x;
  int n = nflag[0];
  for (int i = blockIdx.x; i < n; i += 512) {
    int r = flist[i];
    __syncthreads();
    xrow[tid] = x[(size_t)r * DDIM + tid];
    __syncthreads();
    float xnr = xnorm[r];
    float bb = 3.4e38f;
    int bi = 0;
    for (int c4 = 0; c4 < 4; ++c4) {
      int m = c4 * 256 + tid;
      const float* er = emb + (size_t)m * DDIM;
      float d = 0.0f;
      for (int k = 0; k < DDIM; ++k) d = fmaf(xrow[k], er[k], d);
      float T = __fadd_rn(enorm[m], xnr);
      float s = __fadd_rn(T, __fmul_rn(-2.0f, d));
      if (s < bb || (s == bb && m < bi)) { bb = s; bi = m; }
    }
    rv[tid] = bb; ri[tid] = bi;
    __syncthreads();
    for (int st = 128; st > 0; st >>= 1) {
      if (tid < st) {
        float v = rv[tid + st]; int m2 = ri[tid + st];
        if (v < rv[tid] || (v == rv[tid] && m2 < ri[tid])) { rv[tid] = v; ri[tid] = m2; }
      }
      __syncthreads();
    }
    if (tid == 0) { idx_out[r] = ri[0]; out_idxf[r] = (float)ri[0]; }
  }
}

// ---------------- Kernel 5: gather + quantized_st + per-block loss partials (validated) ----------------
__global__ __launch_bounds__(256)
void gather_loss_kernel(const float* __restrict__ x, const float* __restrict__ emb,
                        const int* __restrict__ idx, float* __restrict__ qout,
                        float* __restrict__ counts,
                        float* __restrict__ loss_part, float* __restrict__ np_part) {
  int lane = threadIdx.x & 63;
  int wav = threadIdx.x >> 6;
  float lsum = 0.0f, nsum = 0.0f;
  #pragma unroll
  for (int it = 0; it < 4; ++it) {
    int row = blockIdx.x * 16 + it * 4 + wav;
    int id = idx[row];
    const float4* xr = (const float4*)(x + (size_t)row * DDIM);
    const float4* er = (const float4*)(emb + (size_t)id * DDIM);
    float4 xv = xr[lane];
    float4 ev = er[lane];
    float4 q;
    q.x = __fadd_rn(xv.x, __fadd_rn(ev.x, -xv.x));
    q.y = __fadd_rn(xv.y, __fadd_rn(ev.y, -xv.y));
    q.z = __fadd_rn(xv.z, __fadd_rn(ev.z, -xv.z));
    q.w = __fadd_rn(xv.w, __fadd_rn(ev.w, -xv.w));
    ((float4*)qout)[(size_t)row * 64 + lane] = q;

    float d0 = xv.x - ev.x, d1 = xv.y - ev.y, d2 = xv.z - ev.z, d3 = xv.w - ev.w;
    float loc = d0 * d0 + d1 * d1 + d2 * d2 + d3 * d3;
    float la = fabsf(xv.x) + fabsf(xv.y) + fabsf(xv.z) + fabsf(xv.w);
    #pragma unroll
    for (int off = 32; off > 0; off >>= 1) {
      loc += __shfl_xor(loc, off, 64);
      la += __shfl_xor(la, off, 64);
    }
    if (lane == 0) {
      float np = (la > 0.0f) ? 1.0f : 0.0f;
      lsum += (loc * (1.0f / 256.0f)) * np;
      nsum += np;
      atomicAdd(&counts[id], 1.0f);
    }
  }
  __shared__ float red[8];
  if (lane == 0) { red[wav] = lsum; red[4 + wav] = nsum; }
  __syncthreads();
  if (threadIdx.x == 0) {
    loss_part[blockIdx.x] = (red[0] + red[1]) + (red[2] + red[3]);
    np_part[blockIdx.x] = (red[4] + red[5]) + (red[6] + red[7]);
  }
}

// ---------------- Kernel 6: finalize loss + perplexity ----------------
#define NPART 4096
__global__ __launch_bounds__(256)
void finalize_kernel(const float* __restrict__ counts,
                     const float* __restrict__ loss_part, const float* __restrict__ np_part,
                     float* __restrict__ out_loss, float* __restrict__ out_perp) {
  __shared__ float red[768];
  int t = threadIdx.x;
  float esum = 0.0f, lsum = 0.0f, nsum = 0.0f;
  for (int m = t; m < MCODES; m += 256) {
    float p = counts[m] * (1.0f / 65536.0f);
    esum += p * logf(p + 1e-10f);
  }
  for (int i = t; i < NPART; i += 256) {
    lsum += loss_part[i];
    nsum += np_part[i];
  }
  red[t] = esum; red[256 + t] = lsum; red[512 + t] = nsum;
  __syncthreads();
  for (int s = 128; s > 0; s >>= 1) {
    if (t < s) {
      red[t] += red[t + s];
      red[256 + t] += red[256 + t + s];
      red[512 + t] += red[512 + t + s];
    }
    __syncthreads();
  }
  if (t == 0) {
    *out_perp = expf(-red[0]);
    *out_loss = 0.25f * red[256] / red[512];
  }
}

extern "C" void kernel_launch(void* const* d_in, const int* in_sizes, int n_in,
                              void* d_out, int out_size, void* d_ws, size_t ws_size,
                              hipStream_t stream) {
  (void)in_sizes; (void)n_in; (void)out_size; (void)ws_size;
  const float* x = (const float*)d_in[0];
  const float* emb = (const float*)d_in[1];

  float* out = (float*)d_out;
  float* qst = out;                   // 16777216
  float* out_loss = out + 16777216;   // 1
  float* out_idxf = out + 16777217;   // 65536
  float* out_perp = out + 16842753;   // 1

  float* ws = (float*)d_ws;
  float* xnorm = ws;                        // 65536
  float* enorm = ws + 65536;                // 1024
  int* idx = (int*)(ws + 66560);            // 65536
  float* counts = ws + 132096;              // 1024
  float* lpart = ws + 133120;               // 4096
  float* npart = ws + 137216;               // 4096
  int* nflag = (int*)(ws + 141312);         // 16
  int* flist = (int*)(ws + 141328);         // 65536
  unsigned short* eimg = (unsigned short*)(ws + 206864);  // 1 MB, 16B-aligned

  norms_init_kernel<<<4160, 256, 0, stream>>>(x, emb, xnorm, enorm, counts, nflag);
  eimg_kernel<<<256, 256, 0, stream>>>(emb, eimg);
  score_kernel<<<512, 256, 0, stream>>>(x, xnorm, enorm, eimg, idx, out_idxf, nflag, flist);
  rescore_kernel<<<512, 256, 0, stream>>>(x, emb, xnorm, enorm, idx, out_idxf, nflag, flist);
  gather_loss_kernel<<<4096, 256, 0, stream>>>(x, emb, idx, qst, counts, lpart, npart);
  finalize_kernel<<<1, 256, 0, stream>>>(counts, lpart, npart, out_loss, out_perp);
}

// Round 4
// 331.108 us; speedup vs baseline: 6.8246x; 1.1280x over previous
//
#include <hip/hip_runtime.h>

#define BROWS 65536
#define DDIM 256
#define MCODES 1024
#define EPS_MARGIN 1e-4f

typedef __attribute__((ext_vector_type(8))) short short8;   // bf16x8 MFMA frag
typedef __attribute__((ext_vector_type(4))) float float4v;  // fp32x4 acc

__device__ inline unsigned short f2bf_rne(float f) {
  unsigned u = __float_as_uint(f);
  unsigned r = u + 0x7FFFu + ((u >> 16) & 1u);
  return (unsigned short)(r >> 16);
}

// ---------------- Kernel 1: numpy-exact pairwise row norms + zero-init (validated) ----------------
__global__ __launch_bounds__(256)
void norms_init_kernel(const float* __restrict__ x, const float* __restrict__ emb,
                       float* __restrict__ xnorm, float* __restrict__ enorm,
                       float* __restrict__ counts, int* __restrict__ nflag) {
  int t = blockIdx.x * 256 + threadIdx.x;
  if (t < MCODES) counts[t] = 0.0f;
  if (t == 0) *nflag = 0;
  int row = t >> 4;
  int lane = t & 15;
  const float* p;
  float* dst;
  int r;
  if (row < BROWS) { p = x + (size_t)row * DDIM; dst = xnorm; r = row; }
  else             { p = emb + (size_t)(row - BROWS) * DDIM; dst = enorm; r = row - BROWS; }
  int half = (lane >> 3) & 1;
  int j = lane & 7;
  const float* q = p + half * 128 + j;
  float v = q[0];
  float acc = __fmul_rn(v, v);
  #pragma unroll
  for (int i = 1; i < 16; ++i) {
    v = q[i * 8];
    acc = __fadd_rn(acc, __fmul_rn(v, v));
  }
  float o;
  o = __shfl_xor(acc, 1, 64); acc = __fadd_rn(acc, o);
  o = __shfl_xor(acc, 2, 64); acc = __fadd_rn(acc, o);
  o = __shfl_xor(acc, 4, 64); acc = __fadd_rn(acc, o);
  o = __shfl_xor(acc, 8, 64); acc = __fadd_rn(acc, o);
  if (lane == 0) dst[r] = acc;
}

// ---------------- Kernel 2: e-fragment image precompute + embT transpose ----------------
// blocks 0..255: eimg chunks (as round 3, validated layout).
// blocks 256..511: embT[k*1024+m] = emb[m*256+k] (exact copy for coalesced rescore).
__global__ __launch_bounds__(256)
void eimg_kernel(const float* __restrict__ emb, unsigned short* __restrict__ img,
                 float* __restrict__ embT) {
  int b = blockIdx.x;
  if (b < 256) {
    int t = b * 256 + threadIdx.x;  // 65536 chunks
    int lane = t & 63;
    int tile = (t >> 6) & 1;
    int spl = (t >> 7) & 1;
    int kstep = (t >> 8) & 7;
    int cc = t >> 11;
    int code = cc * 32 + tile * 16 + (lane & 15);
    int kb = kstep * 32 + (lane >> 4) * 8;
    const float* src = emb + (size_t)code * DDIM + kb;
    union { unsigned short u[8]; uint4 v; } out;
    #pragma unroll
    for (int j = 0; j < 8; ++j) {
      float f = src[j];
      unsigned short h = f2bf_rne(f);
      if (spl == 0) out.u[j] = h;
      else {
        float r = __fadd_rn(f, -__uint_as_float((unsigned)h << 16));
        out.u[j] = f2bf_rne(r);
      }
    }
    ((uint4*)img)[t] = out.v;
  } else {
    int t = (b - 256) * 256 + threadIdx.x;  // 65536
    int base = t * 4;                        // 4 consecutive embT elements (same k)
    int k = base >> 10;
    int m = base & 1023;
    float4 v;
    v.x = emb[(size_t)(m + 0) * DDIM + k];
    v.y = emb[(size_t)(m + 1) * DDIM + k];
    v.z = emb[(size_t)(m + 2) * DDIM + k];
    v.w = emb[(size_t)(m + 3) * DDIM + k];
    *(float4*)&embT[base] = v;
  }
}

// ---------------- Kernel 3: MFMA split-bf16 score + argmin + flag ----------------
// Per-cc staging: 32KB (8 ks-steps) double-buffered, ONE barrier per cc (32 total).
// Prefetch of cc+1 issued immediately after the barrier -> 465 MFMA cycles to hide it.
__global__ __launch_bounds__(256, 2)
void score_kernel(const float* __restrict__ x, const float* __restrict__ xnorm,
                  const float* __restrict__ enorm_g, const unsigned short* __restrict__ eimg,
                  int* __restrict__ idx_out, float* __restrict__ out_idxf,
                  int* __restrict__ nflag, int* __restrict__ flist) {
  __shared__ __align__(16) unsigned short ebuf[2][16384];  // 2 x 32KB
  __shared__ float enorm_s[MCODES];

  int tid = threadIdx.x;
  int w = tid >> 6;
  int lane = tid & 63;
  int quad = lane >> 4;
  int rowBase = blockIdx.x * 128;
  int waveRow = rowBase + w * 32;

  for (int i = tid; i < MCODES; i += 256) enorm_s[i] = enorm_g[i];

  // ---- A-frag preload: rows waveRow + rg*16 + (lane&15), k = ks*32 + quad*8 + j ----
  short8 xh[2][8], xl[2][8];
  const float* xbase = x + (size_t)(waveRow + (lane & 15)) * DDIM + quad * 8;
  #pragma unroll
  for (int rg = 0; rg < 2; ++rg) {
    #pragma unroll
    for (int ks = 0; ks < 8; ++ks) {
      const float4* p = (const float4*)(xbase + rg * 16 * DDIM + ks * 32);
      float4 v0 = p[0], v1 = p[1];
      float vv[8] = {v0.x, v0.y, v0.z, v0.w, v1.x, v1.y, v1.z, v1.w};
      short8 h8, l8;
      #pragma unroll
      for (int j = 0; j < 8; ++j) {
        unsigned short h = f2bf_rne(vv[j]);
        h8[j] = (short)h;
        float r = __fadd_rn(vv[j], -__uint_as_float((unsigned)h << 16));
        l8[j] = (short)f2bf_rne(r);
      }
      xh[rg][ks] = h8;
      xl[rg][ks] = l8;
    }
  }

  float xn[2][4];
  #pragma unroll
  for (int rg = 0; rg < 2; ++rg)
    #pragma unroll
    for (int reg = 0; reg < 4; ++reg)
      xn[rg][reg] = xnorm[waveRow + rg * 16 + quad * 4 + reg];

  float b1[2][4], b2[2][4];
  int i1[2][4];
  #pragma unroll
  for (int rg = 0; rg < 2; ++rg)
    #pragma unroll
    for (int reg = 0; reg < 4; ++reg) { b1[rg][reg] = 3.4e38f; b2[rg][reg] = 3.4e38f; i1[rg][reg] = 0; }

  // stage one full cc chunk (16384 shorts): wave w covers [w*4096, (w+1)*4096),
  // 8 instructions of 1KB each, dest = wave-uniform base + lane*16B.
  #define STAGE_CC(ccv, bf) do { \
    const unsigned short* g_ = eimg + (size_t)(ccv) * 16384 + w * 4096 + lane * 8; \
    unsigned short* l_ = &ebuf[(bf)][w * 4096]; \
    _Pragma("unroll") \
    for (int j_ = 0; j_ < 8; ++j_) { \
      __builtin_amdgcn_global_load_lds((const __attribute__((address_space(1))) unsigned int*)(g_ + j_ * 512), \
                                       (__attribute__((address_space(3))) unsigned int*)(l_ + j_ * 512), 16, 0, 0); \
    } \
  } while (0)

  STAGE_CC(0, 0);

  for (int cc = 0; cc < 32; ++cc) {
    int buf = cc & 1;
    __syncthreads();                 // drains stage(cc); all waves done reading buf^1
    if (cc < 31) STAGE_CC(cc + 1, buf ^ 1);

    float4v acc[2][2];
    #pragma unroll
    for (int rg = 0; rg < 2; ++rg)
      #pragma unroll
      for (int t2 = 0; t2 < 2; ++t2) acc[rg][t2] = (float4v){0.f, 0.f, 0.f, 0.f};

    #pragma unroll
    for (int ks = 0; ks < 8; ++ks) {
      const unsigned short* sb = &ebuf[buf][ks * 2048];
      short8 eh[2], el[2];
      #pragma unroll
      for (int t2 = 0; t2 < 2; ++t2) {
        eh[t2] = *(const short8*)&sb[0 * 1024 + t2 * 512 + lane * 8];
        el[t2] = *(const short8*)&sb[1 * 1024 + t2 * 512 + lane * 8];
      }
      #pragma unroll
      for (int rg = 0; rg < 2; ++rg)
        #pragma unroll
        for (int t2 = 0; t2 < 2; ++t2) {
          acc[rg][t2] = __builtin_amdgcn_mfma_f32_16x16x32_bf16(xh[rg][ks], eh[t2], acc[rg][t2], 0, 0, 0);
          acc[rg][t2] = __builtin_amdgcn_mfma_f32_16x16x32_bf16(xl[rg][ks], eh[t2], acc[rg][t2], 0, 0, 0);
          acc[rg][t2] = __builtin_amdgcn_mfma_f32_16x16x32_bf16(xh[rg][ks], el[t2], acc[rg][t2], 0, 0, 0);
        }
    }

    // epilogue: scores + best/second-best (codes ascending: t2 then cc)
    #pragma unroll
    for (int t2 = 0; t2 < 2; ++t2) {
      int m = cc * 32 + t2 * 16 + (lane & 15);
      float en = enorm_s[m];
      #pragma unroll
      for (int rg = 0; rg < 2; ++rg)
        #pragma unroll
        for (int reg = 0; reg < 4; ++reg) {
          float T = __fadd_rn(en, xn[rg][reg]);
          float s = __fadd_rn(T, __fmul_rn(-2.0f, acc[rg][t2][reg]));
          if (s < b1[rg][reg]) { b2[rg][reg] = b1[rg][reg]; b1[rg][reg] = s; i1[rg][reg] = m; }
          else { b2[rg][reg] = fminf(b2[rg][reg], s); }
        }
    }
  }

  // cross-lane argmin over the 16 cols (lanes within a quad group)
  #pragma unroll
  for (int off = 1; off < 16; off <<= 1) {
    #pragma unroll
    for (int rg = 0; rg < 2; ++rg)
      #pragma unroll
      for (int reg = 0; reg < 4; ++reg) {
        float ob1 = __shfl_xor(b1[rg][reg], off, 64);
        float ob2 = __shfl_xor(b2[rg][reg], off, 64);
        int oi = __shfl_xor(i1[rg][reg], off, 64);
        float cb1 = b1[rg][reg], cb2 = b2[rg][reg];
        int ci = i1[rg][reg];
        float nb1, nb2; int ni;
        if (ob1 < cb1)      { nb1 = ob1; ni = oi; nb2 = fminf(cb1, ob2); }
        else if (cb1 < ob1) { nb1 = cb1; ni = ci; nb2 = fminf(ob1, cb2); }
        else                { nb1 = cb1; ni = min(ci, oi); nb2 = cb1; }  // tie -> flag
        b1[rg][reg] = nb1; b2[rg][reg] = nb2; i1[rg][reg] = ni;
      }
  }

  if ((lane & 15) == 0) {
    #pragma unroll
    for (int rg = 0; rg < 2; ++rg)
      #pragma unroll
      for (int reg = 0; reg < 4; ++reg) {
        int row = waveRow + rg * 16 + quad * 4 + reg;
        int bi = i1[rg][reg];
        idx_out[row] = bi;
        out_idxf[row] = (float)bi;
        if (__fadd_rn(b2[rg][reg], -b1[rg][reg]) <= EPS_MARGIN) {
          int p = atomicAdd(nflag, 1);
          flist[p] = row;
        }
      }
  }
  #undef STAGE_CC
}

// ---------------- Kernel 4: exact fp32 rescore for flagged rows (coalesced via embT) ----------------
// Bit-identical fmaf sequence to the validated round-1/2 path: sequential k=0..255,
// s = fl(fl(en+xn) - 2*d), strict-<-with-lowest-index argmin. embT[k*1024+m]==emb[m*256+k].
__global__ __launch_bounds__(256)
void rescore_kernel(const float* __restrict__ x, const float* __restrict__ embT,
                    const float* __restrict__ xnorm, const float* __restrict__ enorm,
                    int* __restrict__ idx_out, float* __restrict__ out_idxf,
                    const int* __restrict__ nflag, const int* __restrict__ flist) {
  __shared__ float xrow[DDIM];
  __shared__ float rv[256];
  __shared__ int ri[256];
  int tid = threadIdx.x;
  int n = nflag[0];
  for (int i = blockIdx.x; i < n; i += 512) {
    int r = flist[i];
    __syncthreads();
    xrow[tid] = x[(size_t)r * DDIM + tid];
    __syncthreads();
    float xnr = xnorm[r];
    float bb = 3.4e38f;
    int bi = 0;
    for (int c4 = 0; c4 < 4; ++c4) {
      int m = c4 * 256 + tid;
      float d = 0.0f;
      #pragma unroll 8
      for (int k = 0; k < DDIM; ++k) d = fmaf(xrow[k], embT[k * 1024 + m], d);
      float T = __fadd_rn(enorm[m], xnr);
      float s = __fadd_rn(T, __fmul_rn(-2.0f, d));
      if (s < bb || (s == bb && m < bi)) { bb = s; bi = m; }
    }
    rv[tid] = bb; ri[tid] = bi;
    __syncthreads();
    for (int st = 128; st > 0; st >>= 1) {
      if (tid < st) {
        float v = rv[tid + st]; int m2 = ri[tid + st];
        if (v < rv[tid] || (v == rv[tid] && m2 < ri[tid])) { rv[tid] = v; ri[tid] = m2; }
      }
      __syncthreads();
    }
    if (tid == 0) { idx_out[r] = ri[0]; out_idxf[r] = (float)ri[0]; }
  }
}

// ---------------- Kernel 5: gather + quantized_st + per-block loss partials (validated) ----------------
__global__ __launch_bounds__(256)
void gather_loss_kernel(const float* __restrict__ x, const float* __restrict__ emb,
                        const int* __restrict__ idx, float* __restrict__ qout,
                        float* __restrict__ counts,
                        float* __restrict__ loss_part, float* __restrict__ np_part) {
  int lane = threadIdx.x & 63;
  int wav = threadIdx.x >> 6;
  float lsum = 0.0f, nsum = 0.0f;
  #pragma unroll
  for (int it = 0; it < 4; ++it) {
    int row = blockIdx.x * 16 + it * 4 + wav;
    int id = idx[row];
    const float4* xr = (const float4*)(x + (size_t)row * DDIM);
    const float4* er = (const float4*)(emb + (size_t)id * DDIM);
    float4 xv = xr[lane];
    float4 ev = er[lane];
    float4 q;
    q.x = __fadd_rn(xv.x, __fadd_rn(ev.x, -xv.x));
    q.y = __fadd_rn(xv.y, __fadd_rn(ev.y, -xv.y));
    q.z = __fadd_rn(xv.z, __fadd_rn(ev.z, -xv.z));
    q.w = __fadd_rn(xv.w, __fadd_rn(ev.w, -xv.w));
    ((float4*)qout)[(size_t)row * 64 + lane] = q;

    float d0 = xv.x - ev.x, d1 = xv.y - ev.y, d2 = xv.z - ev.z, d3 = xv.w - ev.w;
    float loc = d0 * d0 + d1 * d1 + d2 * d2 + d3 * d3;
    float la = fabsf(xv.x) + fabsf(xv.y) + fabsf(xv.z) + fabsf(xv.w);
    #pragma unroll
    for (int off = 32; off > 0; off >>= 1) {
      loc += __shfl_xor(loc, off, 64);
      la += __shfl_xor(la, off, 64);
    }
    if (lane == 0) {
      float np = (la > 0.0f) ? 1.0f : 0.0f;
      lsum += (loc * (1.0f / 256.0f)) * np;
      nsum += np;
      atomicAdd(&counts[id], 1.0f);
    }
  }
  __shared__ float red[8];
  if (lane == 0) { red[wav] = lsum; red[4 + wav] = nsum; }
  __syncthreads();
  if (threadIdx.x == 0) {
    loss_part[blockIdx.x] = (red[0] + red[1]) + (red[2] + red[3]);
    np_part[blockIdx.x] = (red[4] + red[5]) + (red[6] + red[7]);
  }
}

// ---------------- Kernel 6: finalize loss + perplexity ----------------
#define NPART 4096
__global__ __launch_bounds__(256)
void finalize_kernel(const float* __restrict__ counts,
                     const float* __restrict__ loss_part, const float* __restrict__ np_part,
                     float* __restrict__ out_loss, float* __restrict__ out_perp) {
  __shared__ float red[768];
  int t = threadIdx.x;
  float esum = 0.0f, lsum = 0.0f, nsum = 0.0f;
  for (int m = t; m < MCODES; m += 256) {
    float p = counts[m] * (1.0f / 65536.0f);
    esum += p * logf(p + 1e-10f);
  }
  for (int i = t; i < NPART; i += 256) {
    lsum += loss_part[i];
    nsum += np_part[i];
  }
  red[t] = esum; red[256 + t] = lsum; red[512 + t] = nsum;
  __syncthreads();
  for (int s = 128; s > 0; s >>= 1) {
    if (t < s) {
      red[t] += red[t + s];
      red[256 + t] += red[256 + t + s];
      red[512 + t] += red[512 + t + s];
    }
    __syncthreads();
  }
  if (t == 0) {
    *out_perp = expf(-red[0]);
    *out_loss = 0.25f * red[256] / red[512];
  }
}

extern "C" void kernel_launch(void* const* d_in, const int* in_sizes, int n_in,
                              void* d_out, int out_size, void* d_ws, size_t ws_size,
                              hipStream_t stream) {
  (void)in_sizes; (void)n_in; (void)out_size; (void)ws_size;
  const float* x = (const float*)d_in[0];
  const float* emb = (const float*)d_in[1];

  float* out = (float*)d_out;
  float* qst = out;                   // 16777216
  float* out_loss = out + 16777216;   // 1
  float* out_idxf = out + 16777217;   // 65536
  float* out_perp = out + 16842753;   // 1

  float* ws = (float*)d_ws;
  float* xnorm = ws;                        // 65536
  float* enorm = ws + 65536;                // 1024
  int* idx = (int*)(ws + 66560);            // 65536
  float* counts = ws + 132096;              // 1024
  float* lpart = ws + 133120;               // 4096
  float* npart = ws + 137216;               // 4096
  int* nflag = (int*)(ws + 141312);         // 16
  int* flist = (int*)(ws + 141328);         // 65536
  unsigned short* eimg = (unsigned short*)(ws + 206864);  // 1 MB (524288 ushort)
  float* embT = ws + 469008;                // 1 MB (262144 floats)

  norms_init_kernel<<<4160, 256, 0, stream>>>(x, emb, xnorm, enorm, counts, nflag);
  eimg_kernel<<<512, 256, 0, stream>>>(emb, eimg, embT);
  score_kernel<<<512, 256, 0, stream>>>(x, xnorm, enorm, eimg, idx, out_idxf, nflag, flist);
  rescore_kernel<<<512, 256, 0, stream>>>(x, embT, xnorm, enorm, idx, out_idxf, nflag, flist);
  gather_loss_kernel<<<4096, 256, 0, stream>>>(x, emb, idx, qst, counts, lpart, npart);
  finalize_kernel<<<1, 256, 0, stream>>>(counts, lpart, npart, out_loss, out_perp);
}

// Round 5
// 298.514 us; speedup vs baseline: 7.5698x; 1.1092x over previous
//
#include <hip/hip_runtime.h>

#define BROWS 65536
#define DDIM 256
#define MCODES 1024
#define EPS_MARGIN 1e-5f
#define RGRP 8

typedef __attribute__((ext_vector_type(8))) short short8;   // bf16x8 MFMA frag
typedef __attribute__((ext_vector_type(4))) float float4v;  // fp32x4 acc

__device__ inline unsigned short f2bf_rne(float f) {
  unsigned u = __float_as_uint(f);
  unsigned r = u + 0x7FFFu + ((u >> 16) & 1u);
  return (unsigned short)(r >> 16);
}

__device__ inline short8 as_s8(uint4 v) {
  union { uint4 u; short8 s; } x; x.u = v; return x.s;
}

// ---------------- Kernel 1: numpy-exact pairwise row norms + zero-init (validated) ----------------
__global__ __launch_bounds__(256)
void norms_init_kernel(const float* __restrict__ x, const float* __restrict__ emb,
                       float* __restrict__ xnorm, float* __restrict__ enorm,
                       float* __restrict__ counts, int* __restrict__ nflag) {
  int t = blockIdx.x * 256 + threadIdx.x;
  if (t < MCODES) counts[t] = 0.0f;
  if (t == 0) *nflag = 0;
  int row = t >> 4;
  int lane = t & 15;
  const float* p;
  float* dst;
  int r;
  if (row < BROWS) { p = x + (size_t)row * DDIM; dst = xnorm; r = row; }
  else             { p = emb + (size_t)(row - BROWS) * DDIM; dst = enorm; r = row - BROWS; }
  int half = (lane >> 3) & 1;
  int j = lane & 7;
  const float* q = p + half * 128 + j;
  float v = q[0];
  float acc = __fmul_rn(v, v);
  #pragma unroll
  for (int i = 1; i < 16; ++i) {
    v = q[i * 8];
    acc = __fadd_rn(acc, __fmul_rn(v, v));
  }
  float o;
  o = __shfl_xor(acc, 1, 64); acc = __fadd_rn(acc, o);
  o = __shfl_xor(acc, 2, 64); acc = __fadd_rn(acc, o);
  o = __shfl_xor(acc, 4, 64); acc = __fadd_rn(acc, o);
  o = __shfl_xor(acc, 8, 64); acc = __fadd_rn(acc, o);
  if (lane == 0) dst[r] = acc;
}

// ---------------- Kernel 2: e-fragment image precompute + embT transpose (validated) ----------------
__global__ __launch_bounds__(256)
void eimg_kernel(const float* __restrict__ emb, unsigned short* __restrict__ img,
                 float* __restrict__ embT) {
  int b = blockIdx.x;
  if (b < 256) {
    int t = b * 256 + threadIdx.x;  // 65536 chunks
    int lane = t & 63;
    int tile = (t >> 6) & 1;
    int spl = (t >> 7) & 1;
    int kstep = (t >> 8) & 7;
    int cc = t >> 11;
    int code = cc * 32 + tile * 16 + (lane & 15);
    int kb = kstep * 32 + (lane >> 4) * 8;
    const float* src = emb + (size_t)code * DDIM + kb;
    union { unsigned short u[8]; uint4 v; } out;
    #pragma unroll
    for (int j = 0; j < 8; ++j) {
      float f = src[j];
      unsigned short h = f2bf_rne(f);
      if (spl == 0) out.u[j] = h;
      else {
        float r = __fadd_rn(f, -__uint_as_float((unsigned)h << 16));
        out.u[j] = f2bf_rne(r);
      }
    }
    ((uint4*)img)[t] = out.v;
  } else {
    int t = (b - 256) * 256 + threadIdx.x;  // 65536
    int base = t * 4;
    int k = base >> 10;
    int m = base & 1023;
    float4 v;
    v.x = emb[(size_t)(m + 0) * DDIM + k];
    v.y = emb[(size_t)(m + 1) * DDIM + k];
    v.z = emb[(size_t)(m + 2) * DDIM + k];
    v.w = emb[(size_t)(m + 3) * DDIM + k];
    *(float4*)&embT[base] = v;
  }
}

// ---------------- Kernel 3: MFMA split-bf16 score, B direct from global (L2-hot) ----------------
// No LDS staging, no K-loop barriers. B frags loaded with global_load_dwordx4
// (lane-exact eimg layout), depth-2 register prefetch; compiler pipelines with vmcnt.
__global__ __launch_bounds__(256, 2)
void score_kernel(const float* __restrict__ x, const float* __restrict__ xnorm,
                  const float* __restrict__ enorm_g, const unsigned short* __restrict__ eimg,
                  int* __restrict__ idx_out, float* __restrict__ out_idxf,
                  int* __restrict__ nflag, int* __restrict__ flist) {
  __shared__ float enorm_s[MCODES];
  __shared__ int lcount;
  __shared__ int lbase;
  __shared__ int lrows[128];

  int tid = threadIdx.x;
  int w = tid >> 6;
  int lane = tid & 63;
  int quad = lane >> 4;
  int rowBase = blockIdx.x * 128;
  int waveRow = rowBase + w * 32;

  if (tid == 0) lcount = 0;
  for (int i = tid; i < MCODES; i += 256) enorm_s[i] = enorm_g[i];
  __syncthreads();

  // ---- A-frag preload (validated layout): rows waveRow + rg*16 + (lane&15), k = ks*32 + quad*8 + j
  short8 xh[2][8], xl[2][8];
  const float* xbase = x + (size_t)(waveRow + (lane & 15)) * DDIM + quad * 8;
  #pragma unroll
  for (int rg = 0; rg < 2; ++rg) {
    #pragma unroll
    for (int ks = 0; ks < 8; ++ks) {
      const float4* p = (const float4*)(xbase + rg * 16 * DDIM + ks * 32);
      float4 v0 = p[0], v1 = p[1];
      float vv[8] = {v0.x, v0.y, v0.z, v0.w, v1.x, v1.y, v1.z, v1.w};
      short8 h8, l8;
      #pragma unroll
      for (int j = 0; j < 8; ++j) {
        unsigned short h = f2bf_rne(vv[j]);
        h8[j] = (short)h;
        float r = __fadd_rn(vv[j], -__uint_as_float((unsigned)h << 16));
        l8[j] = (short)f2bf_rne(r);
      }
      xh[rg][ks] = h8;
      xl[rg][ks] = l8;
    }
  }

  float xn[2][4];
  #pragma unroll
  for (int rg = 0; rg < 2; ++rg)
    #pragma unroll
    for (int reg = 0; reg < 4; ++reg)
      xn[rg][reg] = xnorm[waveRow + rg * 16 + quad * 4 + reg];

  float b1[2][4], b2[2][4];
  int i1[2][4];
  #pragma unroll
  for (int rg = 0; rg < 2; ++rg)
    #pragma unroll
    for (int reg = 0; reg < 4; ++reg) { b1[rg][reg] = 3.4e38f; b2[rg][reg] = 3.4e38f; i1[rg][reg] = 0; }

  // B frag pointers: chunk index = step*256 + spl*128 + t2*64 + lane, 16B each.
  const uint4* eg = ((const uint4*)eimg) + lane;

  // depth-2 prefetch pipeline
  uint4 pipe[2][4];
  #pragma unroll
  for (int s = 0; s < 2; ++s) {
    const uint4* p = eg + s * 256;
    pipe[s][0] = p[0];    // eh t2=0
    pipe[s][1] = p[64];   // eh t2=1
    pipe[s][2] = p[128];  // el t2=0
    pipe[s][3] = p[192];  // el t2=1
  }

  for (int cc = 0; cc < 32; ++cc) {
    float4v acc[2][2];
    #pragma unroll
    for (int rg = 0; rg < 2; ++rg)
      #pragma unroll
      for (int t2 = 0; t2 < 2; ++t2) acc[rg][t2] = (float4v){0.f, 0.f, 0.f, 0.f};

    #pragma unroll
    for (int ks = 0; ks < 8; ++ks) {
      int step = cc * 8 + ks;
      const int pb = ks & 1;  // == step&1 (cc*8 even)
      uint4 c0 = pipe[pb][0], c1 = pipe[pb][1], c2 = pipe[pb][2], c3 = pipe[pb][3];
      if (step + 2 < 256) {
        const uint4* p = eg + (size_t)(step + 2) * 256;
        pipe[pb][0] = p[0];
        pipe[pb][1] = p[64];
        pipe[pb][2] = p[128];
        pipe[pb][3] = p[192];
      }
      short8 eh[2] = {as_s8(c0), as_s8(c1)};
      short8 el[2] = {as_s8(c2), as_s8(c3)};
      #pragma unroll
      for (int rg = 0; rg < 2; ++rg)
        #pragma unroll
        for (int t2 = 0; t2 < 2; ++t2) {
          acc[rg][t2] = __builtin_amdgcn_mfma_f32_16x16x32_bf16(xh[rg][ks], eh[t2], acc[rg][t2], 0, 0, 0);
          acc[rg][t2] = __builtin_amdgcn_mfma_f32_16x16x32_bf16(xl[rg][ks], eh[t2], acc[rg][t2], 0, 0, 0);
          acc[rg][t2] = __builtin_amdgcn_mfma_f32_16x16x32_bf16(xh[rg][ks], el[t2], acc[rg][t2], 0, 0, 0);
        }
    }

    // epilogue: scores + best/second-best (codes ascending: t2 then cc)
    #pragma unroll
    for (int t2 = 0; t2 < 2; ++t2) {
      int m = cc * 32 + t2 * 16 + (lane & 15);
      float en = enorm_s[m];
      #pragma unroll
      for (int rg = 0; rg < 2; ++rg)
        #pragma unroll
        for (int reg = 0; reg < 4; ++reg) {
          float T = __fadd_rn(en, xn[rg][reg]);
          float s = __fadd_rn(T, __fmul_rn(-2.0f, acc[rg][t2][reg]));
          if (s < b1[rg][reg]) { b2[rg][reg] = b1[rg][reg]; b1[rg][reg] = s; i1[rg][reg] = m; }
          else { b2[rg][reg] = fminf(b2[rg][reg], s); }
        }
    }
  }

  // cross-lane argmin over the 16 cols (lanes within a quad group)
  #pragma unroll
  for (int off = 1; off < 16; off <<= 1) {
    #pragma unroll
    for (int rg = 0; rg < 2; ++rg)
      #pragma unroll
      for (int reg = 0; reg < 4; ++reg) {
        float ob1 = __shfl_xor(b1[rg][reg], off, 64);
        float ob2 = __shfl_xor(b2[rg][reg], off, 64);
        int oi = __shfl_xor(i1[rg][reg], off, 64);
        float cb1 = b1[rg][reg], cb2 = b2[rg][reg];
        int ci = i1[rg][reg];
        float nb1, nb2; int ni;
        if (ob1 < cb1)      { nb1 = ob1; ni = oi; nb2 = fminf(cb1, ob2); }
        else if (cb1 < ob1) { nb1 = cb1; ni = ci; nb2 = fminf(ob1, cb2); }
        else                { nb1 = cb1; ni = min(ci, oi); nb2 = cb1; }  // tie -> flag
        b1[rg][reg] = nb1; b2[rg][reg] = nb2; i1[rg][reg] = ni;
      }
  }

  if ((lane & 15) == 0) {
    #pragma unroll
    for (int rg = 0; rg < 2; ++rg)
      #pragma unroll
      for (int reg = 0; reg < 4; ++reg) {
        int row = waveRow + rg * 16 + quad * 4 + reg;
        int bi = i1[rg][reg];
        idx_out[row] = bi;
        out_idxf[row] = (float)bi;
        if (__fadd_rn(b2[rg][reg], -b1[rg][reg]) <= EPS_MARGIN) {
          int p = atomicAdd(&lcount, 1);  // LDS atomic — fast
          lrows[p] = row;
        }
      }
  }
  __syncthreads();
  if (tid == 0 && lcount > 0) lbase = atomicAdd(nflag, lcount);  // one global atomic/block
  __syncthreads();
  if (tid < lcount) flist[lbase + tid] = lrows[tid];
}

// ---------------- Kernel 4: batched exact fp32 rescore (groups of 8 rows share embT stream) ----------------
// Per (row,code): d = sequential fmaf k=0..255 (bit-identical to validated order),
// s = fl(fl(en+xn) - 2*d), strict-<-with-lowest-index argmin.
__global__ __launch_bounds__(256)
void rescore_kernel(const float* __restrict__ x, const float* __restrict__ embT,
                    const float* __restrict__ xnorm, const float* __restrict__ enorm,
                    int* __restrict__ idx_out, float* __restrict__ out_idxf,
                    const int* __restrict__ nflag, const int* __restrict__ flist) {
  __shared__ float xs[RGRP][DDIM];
  __shared__ float xnr[RGRP];
  __shared__ int rown[RGRP];
  __shared__ float rv[RGRP][256];
  __shared__ int ri[RGRP][256];
  int tid = threadIdx.x;
  int n = nflag[0];

  for (int g = blockIdx.x; g * RGRP < n; g += 1024) {
    int base = g * RGRP;
    int cnt = min(RGRP, n - base);
    __syncthreads();
    if (tid < RGRP) {
      int rr = flist[base + min(tid, cnt - 1)];
      rown[tid] = rr;
      xnr[tid] = xnorm[rr];
    }
    __syncthreads();
    #pragma unroll
    for (int r = 0; r < RGRP; ++r) xs[r][tid] = x[(size_t)rown[r] * DDIM + tid];
    __syncthreads();

    float d[4][RGRP];
    #pragma unroll
    for (int c4 = 0; c4 < 4; ++c4)
      #pragma unroll
      for (int r = 0; r < RGRP; ++r) d[c4][r] = 0.0f;

    for (int k0 = 0; k0 < DDIM; k0 += 4) {
      float e[4][4];  // [kk][c4]
      #pragma unroll
      for (int kk = 0; kk < 4; ++kk)
        #pragma unroll
        for (int c4 = 0; c4 < 4; ++c4)
          e[kk][c4] = embT[(size_t)(k0 + kk) * 1024 + c4 * 256 + tid];
      float4 xv[RGRP];
      #pragma unroll
      for (int r = 0; r < RGRP; ++r) xv[r] = *(const float4*)&xs[r][k0];
      #pragma unroll
      for (int r = 0; r < RGRP; ++r) {
        float xa[4] = {xv[r].x, xv[r].y, xv[r].z, xv[r].w};
        #pragma unroll
        for (int c4 = 0; c4 < 4; ++c4) {
          // k ascending within the chain for fixed (r, c4)
          d[c4][r] = fmaf(xa[0], e[0][c4], d[c4][r]);
          d[c4][r] = fmaf(xa[1], e[1][c4], d[c4][r]);
          d[c4][r] = fmaf(xa[2], e[2][c4], d[c4][r]);
          d[c4][r] = fmaf(xa[3], e[3][c4], d[c4][r]);
        }
      }
    }

    float b[RGRP]; int bi[RGRP];
    #pragma unroll
    for (int r = 0; r < RGRP; ++r) { b[r] = 3.4e38f; bi[r] = 0; }
    #pragma unroll
    for (int c4 = 0; c4 < 4; ++c4) {
      int m = c4 * 256 + tid;
      float en = enorm[m];
      #pragma unroll
      for (int r = 0; r < RGRP; ++r) {
        float T = __fadd_rn(en, xnr[r]);
        float s = __fadd_rn(T, __fmul_rn(-2.0f, d[c4][r]));
        if (s < b[r] || (s == b[r] && m < bi[r])) { b[r] = s; bi[r] = m; }
      }
    }
    #pragma unroll
    for (int r = 0; r < RGRP; ++r) { rv[r][tid] = b[r]; ri[r][tid] = bi[r]; }
    __syncthreads();
    for (int st = 128; st > 0; st >>= 1) {
      if (tid < st) {
        #pragma unroll
        for (int r = 0; r < RGRP; ++r) {
          float v = rv[r][tid + st]; int m2 = ri[r][tid + st];
          if (v < rv[r][tid] || (v == rv[r][tid] && m2 < ri[r][tid])) { rv[r][tid] = v; ri[r][tid] = m2; }
        }
      }
      __syncthreads();
    }
    if (tid < cnt) {
      idx_out[rown[tid]] = ri[tid][0];
      out_idxf[rown[tid]] = (float)ri[tid][0];
    }
  }
}

// ---------------- Kernel 5: gather + quantized_st + per-block loss partials (validated) ----------------
__global__ __launch_bounds__(256)
void gather_loss_kernel(const float* __restrict__ x, const float* __restrict__ emb,
                        const int* __restrict__ idx, float* __restrict__ qout,
                        float* __restrict__ counts,
                        float* __restrict__ loss_part, float* __restrict__ np_part) {
  int lane = threadIdx.x & 63;
  int wav = threadIdx.x >> 6;
  float lsum = 0.0f, nsum = 0.0f;
  #pragma unroll
  for (int it = 0; it < 4; ++it) {
    int row = blockIdx.x * 16 + it * 4 + wav;
    int id = idx[row];
    const float4* xr = (const float4*)(x + (size_t)row * DDIM);
    const float4* er = (const float4*)(emb + (size_t)id * DDIM);
    float4 xv = xr[lane];
    float4 ev = er[lane];
    float4 q;
    q.x = __fadd_rn(xv.x, __fadd_rn(ev.x, -xv.x));
    q.y = __fadd_rn(xv.y, __fadd_rn(ev.y, -xv.y));
    q.z = __fadd_rn(xv.z, __fadd_rn(ev.z, -xv.z));
    q.w = __fadd_rn(xv.w, __fadd_rn(ev.w, -xv.w));
    ((float4*)qout)[(size_t)row * 64 + lane] = q;

    float d0 = xv.x - ev.x, d1 = xv.y - ev.y, d2 = xv.z - ev.z, d3 = xv.w - ev.w;
    float loc = d0 * d0 + d1 * d1 + d2 * d2 + d3 * d3;
    float la = fabsf(xv.x) + fabsf(xv.y) + fabsf(xv.z) + fabsf(xv.w);
    #pragma unroll
    for (int off = 32; off > 0; off >>= 1) {
      loc += __shfl_xor(loc, off, 64);
      la += __shfl_xor(la, off, 64);
    }
    if (lane == 0) {
      float np = (la > 0.0f) ? 1.0f : 0.0f;
      lsum += (loc * (1.0f / 256.0f)) * np;
      nsum += np;
      atomicAdd(&counts[id], 1.0f);
    }
  }
  __shared__ float red[8];
  if (lane == 0) { red[wav] = lsum; red[4 + wav] = nsum; }
  __syncthreads();
  if (threadIdx.x == 0) {
    loss_part[blockIdx.x] = (red[0] + red[1]) + (red[2] + red[3]);
    np_part[blockIdx.x] = (red[4] + red[5]) + (red[6] + red[7]);
  }
}

// ---------------- Kernel 6: finalize loss + perplexity ----------------
#define NPART 4096
__global__ __launch_bounds__(256)
void finalize_kernel(const float* __restrict__ counts,
                     const float* __restrict__ loss_part, const float* __restrict__ np_part,
                     float* __restrict__ out_loss, float* __restrict__ out_perp) {
  __shared__ float red[768];
  int t = threadIdx.x;
  float esum = 0.0f, lsum = 0.0f, nsum = 0.0f;
  for (int m = t; m < MCODES; m += 256) {
    float p = counts[m] * (1.0f / 65536.0f);
    esum += p * logf(p + 1e-10f);
  }
  for (int i = t; i < NPART; i += 256) {
    lsum += loss_part[i];
    nsum += np_part[i];
  }
  red[t] = esum; red[256 + t] = lsum; red[512 + t] = nsum;
  __syncthreads();
  for (int s = 128; s > 0; s >>= 1) {
    if (t < s) {
      red[t] += red[t + s];
      red[256 + t] += red[256 + t + s];
      red[512 + t] += red[512 + t + s];
    }
    __syncthreads();
  }
  if (t == 0) {
    *out_perp = expf(-red[0]);
    *out_loss = 0.25f * red[256] / red[512];
  }
}

extern "C" void kernel_launch(void* const* d_in, const int* in_sizes, int n_in,
                              void* d_out, int out_size, void* d_ws, size_t ws_size,
                              hipStream_t stream) {
  (void)in_sizes; (void)n_in; (void)out_size; (void)ws_size;
  const float* x = (const float*)d_in[0];
  const float* emb = (const float*)d_in[1];

  float* out = (float*)d_out;
  float* qst = out;                   // 16777216
  float* out_loss = out + 16777216;   // 1
  float* out_idxf = out + 16777217;   // 65536
  float* out_perp = out + 16842753;   // 1

  float* ws = (float*)d_ws;
  float* xnorm = ws;                        // 65536
  float* enorm = ws + 65536;                // 1024
  int* idx = (int*)(ws + 66560);            // 65536
  float* counts = ws + 132096;              // 1024
  float* lpart = ws + 133120;               // 4096
  float* npart = ws + 137216;               // 4096
  int* nflag = (int*)(ws + 141312);         // 16
  int* flist = (int*)(ws + 141328);         // 65536
  unsigned short* eimg = (unsigned short*)(ws + 206864);  // 1 MB (524288 ushort)
  float* embT = ws + 469008;                // 1 MB (262144 floats)

  norms_init_kernel<<<4160, 256, 0, stream>>>(x, emb, xnorm, enorm, counts, nflag);
  eimg_kernel<<<512, 256, 0, stream>>>(emb, eimg, embT);
  score_kernel<<<512, 256, 0, stream>>>(x, xnorm, enorm, eimg, idx, out_idxf, nflag, flist);
  rescore_kernel<<<1024, 256, 0, stream>>>(x, embT, xnorm, enorm, idx, out_idxf, nflag, flist);
  gather_loss_kernel<<<4096, 256, 0, stream>>>(x, emb, idx, qst, counts, lpart, npart);
  finalize_kernel<<<1, 256, 0, stream>>>(counts, lpart, npart, out_loss, out_perp);
}